// Round 9
// baseline (1488.380 us; speedup 1.0000x reference)
//
#include <hip/hip_runtime.h>
#include <hip/hip_bf16.h>

typedef float f32x4 __attribute__((ext_vector_type(4)));
typedef __bf16 bf16x8v __attribute__((ext_vector_type(8)));
typedef __bf16 bf16x4v __attribute__((ext_vector_type(4)));
typedef unsigned uint2v __attribute__((ext_vector_type(2)));
typedef bf16x8v __attribute__((may_alias)) bf16x8;
typedef bf16x4v __attribute__((may_alias)) bf16x4;
typedef uint2v __attribute__((may_alias)) u32x2;

typedef __attribute__((address_space(1))) const void gvoid_t;
typedef __attribute__((address_space(3))) void lvoid_t;

#define DEVINL __device__ __forceinline__

#define BDIM 2
#define TDIM 2048
#define CDIM 2048
#define NHEAD 16
#define DHEAD 128
#define MROWS 4096
#define WSZ ((size_t)CDIM * CDIM)
#define XSZ ((size_t)MROWS * CDIM)

// barrier without the compiler's conservative vmcnt(0) drain: LDS ops are
// flushed (lgkmcnt), in-flight global prefetch loads stay in flight.
#define BARRIER_LGKM() asm volatile("s_waitcnt lgkmcnt(0)\ns_barrier" ::: "memory")

DEVINL __bf16 f2bf(float f) {
  unsigned u = __builtin_bit_cast(unsigned, f);
  u += 0x7fffu + ((u >> 16) & 1u);  // RNE
  unsigned short h = (unsigned short)(u >> 16);
  return __builtin_bit_cast(__bf16, h);
}

// pack two f32 -> two bf16 (truncation) in one v_perm
DEVINL unsigned pk2bf_trunc(float lo, float hi) {
  return __builtin_amdgcn_perm(__builtin_bit_cast(unsigned, hi),
                               __builtin_bit_cast(unsigned, lo), 0x07060302);
}

DEVINL void gl2lds16(const void* g, void* l) {
  __builtin_amdgcn_global_load_lds((gvoid_t*)g, (lvoid_t*)l, 16, 0, 0);
}

// Per-wave dtype self-detect: every wave loads the SAME 256 B of src
// (L2/L3 broadcast-hot) and votes on bf16-plausible exponents.
DEVINL int wave_detect(const unsigned* __restrict__ w) {
  const int l = threadIdx.x & 63;
  const unsigned word = w[l];
  const unsigned e = (word >> 7) & 0xFFu;
  const int vote = (e >= 0x70u && e <= 0x87u) ? 1 : 0;
  const unsigned long long m = __ballot(vote);
  return (__popcll(m) >= 32) ? 1 : 0;
}

// ---------------------------------------------------------------------------
// Fused prologue (one launch instead of memset+cvt_src+cvt_bias+cvt_wt):
//   blocks [0,4096):      src -> bf16
//   blocks [4096,4128):   biases -> f32 (+ block 4096 zeroes the attn counter)
//   blocks [4128,8224):   4 weights -> bf16 transposed (64x64 LDS tiles)
__global__ __launch_bounds__(256) void prologue(
    const void* __restrict__ src, __bf16* __restrict__ srcbf, int n8,
    const void* __restrict__ b0, const void* __restrict__ b1,
    const void* __restrict__ b2, const void* __restrict__ b3,
    float* __restrict__ biasf, const void* __restrict__ w0,
    const void* __restrict__ w1, const void* __restrict__ w2,
    const void* __restrict__ w3, __bf16* __restrict__ wt,
    int* __restrict__ cnt) {
  __shared__ __attribute__((aligned(16))) __bf16 tile[64][68];
  const int fl = wave_detect((const unsigned*)src);
  const int bi = blockIdx.x;
  if (bi < 4096) {  // src conversion
    const int i = bi * 256 + threadIdx.x;
    if (i >= n8) return;
    if (fl) {
      ((bf16x8*)srcbf)[i] = ((const bf16x8*)src)[i];
    } else {
      const float* f = (const float*)src + (size_t)i * 8;
      bf16x8v v;
#pragma unroll
      for (int j = 0; j < 8; ++j) v[j] = f2bf(f[j]);
      ((bf16x8*)srcbf)[i] = v;
    }
    return;
  }
  if (bi < 4128) {  // bias conversion + counter zero
    if (bi == 4096 && threadIdx.x == 0) *cnt = 0;
    const int i = (bi - 4096) * 256 + threadIdx.x;  // 0..8191
    const void* b = (i < 2048) ? b0 : (i < 4096) ? b1 : (i < 6144) ? b2 : b3;
    const int idx = i & 2047;
    biasf[i] = fl ? (float)((const __bf16*)b)[idx] : ((const float*)b)[idx];
    return;
  }
  // weight transpose: idx -> (z weight, by n-tile, bx k-tile)
  const int idx = bi - 4128;
  const int z = idx >> 10, rem = idx & 1023;
  const int by = rem >> 5, bx = rem & 31;
  const void* W = (z == 0) ? w0 : (z == 1) ? w1 : (z == 2) ? w2 : w3;
  __bf16* Wt = wt + (size_t)z * WSZ;
  const int tx = threadIdx.x & 63, ty = threadIdx.x >> 6;
  const int k0 = bx * 64, n0 = by * 64;
#pragma unroll
  for (int i = ty; i < 64; i += 4) {
    const size_t off = (size_t)(k0 + i) * CDIM + n0 + tx;
    const float v = fl ? (float)((const __bf16*)W)[off] : ((const float*)W)[off];
    tile[i][tx] = f2bf(v);
  }
  __syncthreads();
#pragma unroll
  for (int i = ty; i < 64; i += 4)
    Wt[(size_t)(n0 + i) * CDIM + k0 + tx] = tile[tx][i];
}

// ---------------------------------------------------------------------------
// Half-K PING-PONG GEMM at 3 blocks/CU. R9 change vs R8's ring-3: 2 slots
// per operand (A 2x8KB + B 2x16KB = 48 KiB) -> 3 blocks/CU, 24 waves/CU;
// the QKV grid (768 blocks) is FULLY resident (one round, no tails).
// Rationale: R8 proved occupancy is the lever (1->2 blocks/CU: MfmaUtil
// 33->39, dur 134.6->115.3 with schedule unchanged); m114/m97 show
// cross-block overlap fills barrier-drain windows that in-block scheduling
// cannot (R2-R6: six schedules flat at 1 block/CU). Trade-off: slot parity
// forces vmcnt(0) twice per tile (prefetch distance ~1.5 phases), the m97
// regime — stalls are hidden by the other two resident blocks.
// Schedule per K-tile (halves h0=2kt slot0, h0+1 slot1):
//   P1: ds_read slot0 (A+nf01) | stage h0+1 -> slot1 | lgkm-bar | MFMA | bar
//   P2: ds_read slot0 (nf23)   |                      lgkm-bar | MFMA |
//       vmcnt(0) certifies h0+1 | bar
//   P3: ds_read slot1 (A+nf01) | stage h0+2 -> slot0 | lgkm-bar | MFMA | bar
//   P4: ds_read slot1 (nf23)   |                      lgkm-bar | MFMA |
//       vmcnt(0) certifies h0+2 | bar
// Race-freedom: each phase's ds_reads are lgkm-drained before its MFMA, so
// the phase-close barrier certifies them chip-wide; slot-s staging is issued
// only after the barrier that postdates slot-s's last read (P1 write to
// slot1 follows prev-P4 close; P3 write to slot0 follows P2 close).
// LDS pair-line layout + XOR involution and all addressing identical to the
// R5-R8 functionally-verified kernel; measured-zero bank conflicts.
template <int MODE>
__global__ __launch_bounds__(512, 6) void gemmring(
    const __bf16* __restrict__ A, const __bf16* __restrict__ Bt,
    const float* __restrict__ bias, __bf16* __restrict__ qb,
    __bf16* __restrict__ kb, __bf16* __restrict__ vtb,
    const unsigned* __restrict__ srcw, void* __restrict__ outp) {
  constexpr int K = CDIM;
  constexpr int NKT = K / 64;  // 32 K-tiles, 64 halves
  __shared__ __attribute__((aligned(16))) __bf16 Asl[2][128 * 32];
  __shared__ __attribute__((aligned(16))) __bf16 Bsl[2][256 * 32];

  const int tid = threadIdx.x;
  const int w = tid >> 6, l = tid & 63;
  const int quad = l >> 4, l16 = l & 15;
  const int wm = w >> 2, wn = w & 3;  // wave tile 64x64

  const int bid = blockIdx.x;
  const int bm = bid & 31, bn = bid >> 5;  // bm-fastest: B panel L2-shared
  const int m0 = bm * 128, n0 = bn * 256;

  // staging source pre-swizzle (inverse of the pair-line layout)
  const int ls = (tid & 7) ^ ((tid >> 3) & 7);
  const int rbase = 2 * (tid >> 3) + (ls >> 2);  // 0..127
  const int cb8 = (ls & 3) * 8;
  const __bf16* gAh = A + (size_t)(m0 + rbase) * K + cb8;
  const __bf16* gBh = Bt + (size_t)(n0 + rbase) * K + cb8;

  // fragment read addressing (per-lane constant)
  const int L2 = l16 >> 1;
  const int physr = (((l16 & 1) << 2) + quad) ^ L2;
  const int lane_e = L2 * 64 + physr * 8;  // element offset within slot

  __bf16* a0 = (__bf16*)Asl[0];
  __bf16* a1 = (__bf16*)Asl[1];
  __bf16* b0 = (__bf16*)Bsl[0];
  __bf16* b1 = (__bf16*)Bsl[1];

#define STAGE_A(dst, h)                                                   \
  gl2lds16(gAh + (size_t)(((h) >> 1) * 64 + ((h) & 1) * 32), (dst) + w * 512)
#define STAGE_B(dst, h, e)                                                \
  gl2lds16(gBh + (size_t)(e) * 128 * K +                                  \
               (((h) >> 1) * 64 + ((h) & 1) * 32),                        \
           (dst) + (e) * 4096 + w * 512)

  f32x4 acc[4][4];
#pragma unroll
  for (int i = 0; i < 4; ++i)
#pragma unroll
    for (int j = 0; j < 4; ++j) acc[i][j] = (f32x4){0.f, 0.f, 0.f, 0.f};

  // prologue: stage half 0 into slot0; drain; barrier.
  STAGE_A(a0, 0); STAGE_B(b0, 0, 0); STAGE_B(b0, 0, 1);
  asm volatile("s_waitcnt vmcnt(0)" ::: "memory");
  __builtin_amdgcn_sched_barrier(0);
  __builtin_amdgcn_s_barrier();

#define MFMA8(NF0)                                                        \
  __builtin_amdgcn_s_setprio(1);                                          \
  _Pragma("unroll") for (int mi = 0; mi < 4; ++mi) {                      \
    acc[mi][(NF0)] = __builtin_amdgcn_mfma_f32_16x16x32_bf16(             \
        afr[mi], bfr[0], acc[mi][(NF0)], 0, 0, 0);                        \
    acc[mi][(NF0) + 1] = __builtin_amdgcn_mfma_f32_16x16x32_bf16(         \
        afr[mi], bfr[1], acc[mi][(NF0) + 1], 0, 0, 0);                    \
  }                                                                       \
  __builtin_amdgcn_s_setprio(0);

#define LGKM_BAR()                                                        \
  __builtin_amdgcn_s_barrier();                                           \
  asm volatile("s_waitcnt lgkmcnt(0)" ::: "memory");                      \
  __builtin_amdgcn_sched_barrier(0)

#define VM0_BAR()                                                         \
  asm volatile("s_waitcnt vmcnt(0)" ::: "memory");                        \
  __builtin_amdgcn_sched_barrier(0);                                      \
  __builtin_amdgcn_s_barrier()

  for (int kt = 0; kt < NKT; ++kt) {
    const int h0 = 2 * kt;
    const bool st = (kt < NKT - 1);
    bf16x8 afr[4], bfr[2];

    // ---- P1: slot0 (h0), nf0-1; stage h0+1 -> slot1 (slot1's last read
    //      was prev-P4, closed by the prev-P4 barrier).
#pragma unroll
    for (int mi = 0; mi < 4; ++mi)
      afr[mi] = *(const bf16x8*)&a0[(wm * 64 + mi * 16) * 32 + lane_e];
    bfr[0] = *(const bf16x8*)&b0[(wn * 64 + 0 * 16) * 32 + lane_e];
    bfr[1] = *(const bf16x8*)&b0[(wn * 64 + 1 * 16) * 32 + lane_e];
    STAGE_A(a1, h0 + 1); STAGE_B(b1, h0 + 1, 0); STAGE_B(b1, h0 + 1, 1);
    LGKM_BAR();
    MFMA8(0)
    __builtin_amdgcn_s_barrier();

    // ---- P2: slot0 (h0), nf2-3; end-wait certifies h0+1 for P3.
    bfr[0] = *(const bf16x8*)&b0[(wn * 64 + 2 * 16) * 32 + lane_e];
    bfr[1] = *(const bf16x8*)&b0[(wn * 64 + 3 * 16) * 32 + lane_e];
    LGKM_BAR();
    MFMA8(2)
    VM0_BAR();

    // ---- P3: slot1 (h0+1), nf0-1; stage h0+2 -> slot0 (slot0's last read
    //      was P2, closed by the P2-end barrier).
#pragma unroll
    for (int mi = 0; mi < 4; ++mi)
      afr[mi] = *(const bf16x8*)&a1[(wm * 64 + mi * 16) * 32 + lane_e];
    bfr[0] = *(const bf16x8*)&b1[(wn * 64 + 0 * 16) * 32 + lane_e];
    bfr[1] = *(const bf16x8*)&b1[(wn * 64 + 1 * 16) * 32 + lane_e];
    if (st) { STAGE_A(a0, h0 + 2); STAGE_B(b0, h0 + 2, 0); STAGE_B(b0, h0 + 2, 1); }
    LGKM_BAR();
    MFMA8(0)
    __builtin_amdgcn_s_barrier();

    // ---- P4: slot1 (h0+1), nf2-3; end-wait certifies h0+2 for next P1.
    bfr[0] = *(const bf16x8*)&b1[(wn * 64 + 2 * 16) * 32 + lane_e];
    bfr[1] = *(const bf16x8*)&b1[(wn * 64 + 3 * 16) * 32 + lane_e];
    LGKM_BAR();
    MFMA8(2)
    VM0_BAR();
  }
#undef MFMA8
#undef LGKM_BAR
#undef VM0_BAR
#undef STAGE_A
#undef STAGE_B

  if (MODE == 0) {
    // QKV scatter: Q,K -> [b,h,t,d]; V -> [b,h,d,t] (bf16x4). BN=256
    // divides 2048 -> mat uniform per block.
    const int mat = n0 >> 11;  // 0=Q 1=K 2=V
#pragma unroll
    for (int nf = 0; nf < 4; ++nf) {
      const int n = n0 + wn * 64 + nf * 16 + l16;  // 0..6143
      const int nn = n & 2047;
      const int h = nn >> 7, d = nn & 127;
      const float bv = bias[n];
#pragma unroll
      for (int mi = 0; mi < 4; ++mi) {
        const int mbase = m0 + wm * 64 + mi * 16 + quad * 4;
        const int bb = mbase >> 11, t = mbase & 2047;
        if (mat == 2) {
          bf16x4v v4;
#pragma unroll
          for (int r = 0; r < 4; ++r) v4[r] = f2bf(acc[mi][nf][r] + bv);
          *(bf16x4*)&vtb[((size_t)(bb * NHEAD + h) * DHEAD + d) * TDIM + t] = v4;
        } else {
          __bf16* op = (mat == 0) ? qb : kb;
#pragma unroll
          for (int r = 0; r < 4; ++r)
            op[((size_t)(bb * NHEAD + h) * TDIM + t + r) * DHEAD + d] =
                f2bf(acc[mi][nf][r] + bv);
        }
      }
    }
  } else {
    const int ofl = wave_detect(srcw);
#pragma unroll
    for (int nf = 0; nf < 4; ++nf) {
      const int n = n0 + wn * 64 + nf * 16 + l16;
      const float bv = bias[n];
#pragma unroll
      for (int mi = 0; mi < 4; ++mi) {
#pragma unroll
        for (int r = 0; r < 4; ++r) {
          const int m = m0 + wm * 64 + mi * 16 + quad * 4 + r;
          const float v = acc[mi][nf][r] + bv;
          if (ofl) ((__bf16*)outp)[(size_t)m * CDIM + n] = f2bf(v);
          else     ((float*)outp)[(size_t)m * CDIM + n] = v;
        }
      }
    }
  }
}

// ---------------------------------------------------------------------------
// Flash-style causal attention (R7 form: setprio around MFMA clusters,
// defer-max THR=8). Persistent blocks + work-stealing, LDS-staged K/V,
// 2 lgkm-only barriers per s-block, register-double-buffered staging.
// (256,2): kernel needs ~180 regs/wave — forcing 3 waves/EU spills.
__global__ __launch_bounds__(256, 2) void attn(
    const __bf16* __restrict__ Q, const __bf16* __restrict__ K,
    const __bf16* __restrict__ Vt, __bf16* __restrict__ ctx,
    int* __restrict__ cnt) {
  constexpr float CSC = 0.12753139726f;  // log2(e)/sqrt(128)
  __shared__ __attribute__((aligned(16))) __bf16 Kls[64 * 128];   // [s][d]
  __shared__ __attribute__((aligned(16))) __bf16 Vls[128 * 64];   // [d][s]
  __shared__ __attribute__((aligned(16))) __bf16 Pls[4][32 * 64]; // [t][s]
  __shared__ int jobLds;

  const int tid = threadIdx.x;
  const int w = tid >> 6, l = tid & 63, quad = l >> 4, l16 = l & 15;

  const int krow = tid >> 4;                 // 0..15, +16 per pass
  const int kcol = tid & 15;
  const int kldsoff = ((kcol ^ krow) * 8);
  const int vrow = tid >> 3;                 // 0..31, +32 per pass
  const int vcol = tid & 7;
  const int vldsoff = ((vcol ^ (vrow & 7)) * 8);

  for (;;) {
    __syncthreads();
    if (tid == 0) jobLds = atomicAdd(cnt, 1);
    __syncthreads();
    const int j = jobLds;
    if (j >= 512) break;
    const int qt = 15 - (j >> 5);   // all qt=15 jobs first (LPT)
    const int bh = j & 31;
    const int t0w = qt * 128 + w * 32;
    const __bf16* Qbh = Q + (size_t)bh * TDIM * DHEAD;
    const __bf16* Kbh = K + (size_t)bh * TDIM * DHEAD;
    const __bf16* Vbh = Vt + (size_t)bh * TDIM * DHEAD;

    bf16x8 qf[2][4];
#pragma unroll
    for (int tt = 0; tt < 2; ++tt)
#pragma unroll
      for (int ks = 0; ks < 4; ++ks)
        qf[tt][ks] = *(const bf16x8*)(Qbh +
                     (size_t)(t0w + tt * 16 + l16) * DHEAD + ks * 32 + quad * 8);

    f32x4 oacc[8][2];
#pragma unroll
    for (int dt = 0; dt < 8; ++dt)
#pragma unroll
      for (int tt = 0; tt < 2; ++tt) oacc[dt][tt] = (f32x4){0.f, 0.f, 0.f, 0.f};
    float mrow[2] = {-1e30f, -1e30f};
    float lrow[2] = {0.f, 0.f};

    const int nsb = 2 * (qt + 1);

    // prefetch s-block 0 into regs
    bf16x8 kr[4], vr[4];
#pragma unroll
    for (int p = 0; p < 4; ++p)
      kr[p] = *(const bf16x8*)(Kbh + (size_t)(p * 16 + krow) * DHEAD + kcol * 8);
#pragma unroll
    for (int p = 0; p < 4; ++p)
      vr[p] = *(const bf16x8*)(Vbh + (size_t)(p * 32 + vrow) * TDIM + vcol * 8);

    for (int sb = 0; sb < nsb; ++sb) {
      const int s0 = sb * 64;
      BARRIER_LGKM();  // prior iteration's LDS reads complete
#pragma unroll
      for (int p = 0; p < 4; ++p)
        *(bf16x8*)&Kls[(p * 16 + krow) * 128 + kldsoff] = kr[p];
#pragma unroll
      for (int p = 0; p < 4; ++p)
        *(bf16x8*)&Vls[(p * 32 + vrow) * 64 + vldsoff] = vr[p];
      if (sb + 1 < nsb) {
        const int s1 = s0 + 64;
#pragma unroll
        for (int p = 0; p < 4; ++p)
          kr[p] = *(const bf16x8*)(Kbh + (size_t)(s1 + p * 16 + krow) * DHEAD +
                                   kcol * 8);
#pragma unroll
        for (int p = 0; p < 4; ++p)
          vr[p] = *(const bf16x8*)(Vbh + (size_t)(p * 32 + vrow) * TDIM + s1 +
                                   vcol * 8);
      }
      BARRIER_LGKM();  // staging visible; prefetch loads remain in flight
      if (s0 > t0w + 31) continue;  // fully masked for this wave

      // S^T = K.Q^T : D[row=s: quad*4+r][col=t: l16]
      f32x4 sacc[4][2];
#pragma unroll
      for (int st = 0; st < 4; ++st)
#pragma unroll
        for (int tt = 0; tt < 2; ++tt) sacc[st][tt] = (f32x4){0.f, 0.f, 0.f, 0.f};
      __builtin_amdgcn_s_setprio(1);
#pragma unroll
      for (int ks = 0; ks < 4; ++ks) {
        bf16x8 kf[4];
#pragma unroll
        for (int st = 0; st < 4; ++st)
          kf[st] = *(const bf16x8*)&Kls[(st * 16 + l16) * 128 +
                                        (((ks * 4 + quad) ^ l16) * 8)];
#pragma unroll
        for (int st = 0; st < 4; ++st)
#pragma unroll
          for (int tt = 0; tt < 2; ++tt)
            sacc[st][tt] = __builtin_amdgcn_mfma_f32_16x16x32_bf16(
                kf[st], qf[tt][ks], sacc[st][tt], 0, 0, 0);
      }
      __builtin_amdgcn_s_setprio(0);
      if (s0 + 63 > t0w) {  // causal mask near diagonal
#pragma unroll
        for (int st = 0; st < 4; ++st)
#pragma unroll
          for (int tt = 0; tt < 2; ++tt)
#pragma unroll
            for (int r = 0; r < 4; ++r) {
              const int s = s0 + st * 16 + quad * 4 + r;
              const int t = t0w + tt * 16 + l16;
              if (s > t) sacc[st][tt][r] = -1e30f;
            }
      }
      // online softmax per t-column (defer-max: rescale only when growth
      // exceeds 8 exp2-units; P stays bounded by 2^8)
#pragma unroll
      for (int tt = 0; tt < 2; ++tt) {
        float vm = -1e30f;
#pragma unroll
        for (int st = 0; st < 4; ++st)
#pragma unroll
          for (int r = 0; r < 4; ++r) vm = fmaxf(vm, sacc[st][tt][r]);
        vm = fmaxf(vm, __shfl_xor(vm, 16));
        vm = fmaxf(vm, __shfl_xor(vm, 32));
        if (__ballot((vm - mrow[tt]) * CSC > 8.0f)) {
          const float mn = fmaxf(mrow[tt], vm);
          const float alpha = exp2f((mrow[tt] - mn) * CSC);
          lrow[tt] *= alpha;
#pragma unroll
          for (int dt = 0; dt < 8; ++dt)
#pragma unroll
            for (int r = 0; r < 4; ++r) oacc[dt][tt][r] *= alpha;
          mrow[tt] = mn;
        }
        const float mcur = mrow[tt];
        float rs = 0.f;
#pragma unroll
        for (int st = 0; st < 4; ++st) {
          const float p0 = exp2f((sacc[st][tt][0] - mcur) * CSC);
          const float p1 = exp2f((sacc[st][tt][1] - mcur) * CSC);
          const float p2 = exp2f((sacc[st][tt][2] - mcur) * CSC);
          const float p3 = exp2f((sacc[st][tt][3] - mcur) * CSC);
          rs += (p0 + p1) + (p2 + p3);
          u32x2 pk = {pk2bf_trunc(p0, p1), pk2bf_trunc(p2, p3)};
          *(u32x2*)&Pls[w][(tt * 16 + l16) * 64 +
                           (((st * 2 + (quad >> 1)) ^ (l16 & 7)) * 8) +
                           (quad & 1) * 4] = pk;
        }
        rs += __shfl_xor(rs, 16);
        rs += __shfl_xor(rs, 32);
        lrow[tt] += rs;
      }
      // intra-wave P write->read ordering (wave-private region, no barrier)
      asm volatile("s_waitcnt lgkmcnt(0)" ::: "memory");
      // O^T += V^T.P^T : D[row=d][col=t]
      __builtin_amdgcn_s_setprio(1);
#pragma unroll
      for (int ks = 0; ks < 2; ++ks) {
        bf16x8 pf[2];
#pragma unroll
        for (int tt = 0; tt < 2; ++tt)
          pf[tt] = *(const bf16x8*)&Pls[w][(tt * 16 + l16) * 64 +
                                           (((ks * 4 + quad) ^ (l16 & 7)) * 8)];
#pragma unroll
        for (int dt = 0; dt < 8; ++dt) {
          const bf16x8 vf =
              *(const bf16x8*)&Vls[(dt * 16 + l16) * 64 +
                                   (((ks * 4 + quad) ^ (l16 & 7)) * 8)];
#pragma unroll
          for (int tt = 0; tt < 2; ++tt)
            oacc[dt][tt] = __builtin_amdgcn_mfma_f32_16x16x32_bf16(
                vf, pf[tt], oacc[dt][tt], 0, 0, 0);
        }
      }
      __builtin_amdgcn_s_setprio(0);
    }

    // epilogue: O^T[d][t]/l -> ctx[b][t][h*128+d], bf16x4 stores
    const int b = bh >> 4, h = bh & 15;
#pragma unroll
    for (int tt = 0; tt < 2; ++tt) {
      const float rinv = 1.0f / lrow[tt];
      const int t = t0w + tt * 16 + l16;
      __bf16* cp = ctx + ((size_t)(b * TDIM + t)) * CDIM + h * DHEAD;
#pragma unroll
      for (int dt = 0; dt < 8; ++dt) {
        bf16x4v v4;
#pragma unroll
        for (int r = 0; r < 4; ++r) v4[r] = f2bf(oacc[dt][tt][r] * rinv);
        *(bf16x4*)&cp[dt * 16 + quad * 4] = v4;
      }
    }
  }
}

// ---------------------------------------------------------------------------
extern "C" void kernel_launch(void* const* d_in, const int* in_sizes, int n_in,
                              void* d_out, int out_size, void* d_ws,
                              size_t ws_size, hipStream_t stream) {
  const void* src = d_in[0];
  const void* Wq = d_in[1];
  const void* bq = d_in[2];
  const void* Wk = d_in[3];
  const void* bk = d_in[4];
  const void* Wv = d_in[5];
  const void* bv = d_in[6];
  const void* Wo = d_in[7];
  const void* bo = d_in[8];

  char* wsb = (char*)d_ws;
  int* cnt = (int*)(wsb + 128);           // +128 (work-steal counter)
  __bf16* srcbf = (__bf16*)(wsb + 256);
  __bf16* wqt = srcbf + XSZ;              // q,k,v,o transposed, contiguous
  __bf16* wot = wqt + 3 * WSZ;
  __bf16* qb = wot + WSZ;                 // [B*NH][T][D]
  __bf16* kb = qb + XSZ;                  // [B*NH][T][D]
  __bf16* vtb = kb + XSZ;                 // [B*NH][D][T]
  float* biasf = (float*)(vtb + XSZ);     // 4 x 2048 f32
  __bf16* ctx = srcbf;                    // reuse (src consumed by then)

  // fused prologue: src cvt (4096) + bias cvt/cnt-zero (32) + wt transpose
  // (4096) = 8224 blocks, one launch.
  prologue<<<8224, 256, 0, stream>>>(src, srcbf, (int)(XSZ / 8), bq, bk, bv,
                                     bo, biasf, Wq, Wk, Wv, Wo, wqt, cnt);
  // fused QKV: M=4096, N=6144, BM=128 x BN=256 -> 32x24 = 768 blocks
  // (3 blocks/CU resident -> the whole grid runs in ONE round)
  gemmring<0><<<768, 512, 0, stream>>>(srcbf, wqt, biasf, qb, kb, vtb,
                                       nullptr, nullptr);
  attn<<<512, 256, 0, stream>>>(qb, kb, vtb, ctx, cnt);
  // out-proj: M=4096, N=2048 -> 32x8 = 256 blocks
  gemmring<1><<<256, 512, 0, stream>>>(ctx, wot, biasf + 6144, nullptr,
                                       nullptr, nullptr, (const unsigned*)src,
                                       d_out);
}

// Round 10
// 425.623 us; speedup vs baseline: 3.4969x; 3.4969x over previous
//
#include <hip/hip_runtime.h>
#include <hip/hip_bf16.h>

typedef float f32x4 __attribute__((ext_vector_type(4)));
typedef __bf16 bf16x8v __attribute__((ext_vector_type(8)));
typedef __bf16 bf16x4v __attribute__((ext_vector_type(4)));
typedef unsigned uint2v __attribute__((ext_vector_type(2)));
typedef bf16x8v __attribute__((may_alias)) bf16x8;
typedef bf16x4v __attribute__((may_alias)) bf16x4;
typedef uint2v __attribute__((may_alias)) u32x2;

typedef __attribute__((address_space(1))) const void gvoid_t;
typedef __attribute__((address_space(3))) void lvoid_t;

#define DEVINL __device__ __forceinline__

#define BDIM 2
#define TDIM 2048
#define CDIM 2048
#define NHEAD 16
#define DHEAD 128
#define MROWS 4096
#define WSZ ((size_t)CDIM * CDIM)
#define XSZ ((size_t)MROWS * CDIM)

// barrier without the compiler's conservative vmcnt(0) drain: LDS ops are
// flushed (lgkmcnt), in-flight global prefetch loads stay in flight.
#define BARRIER_LGKM() asm volatile("s_waitcnt lgkmcnt(0)\ns_barrier" ::: "memory")

DEVINL __bf16 f2bf(float f) {
  unsigned u = __builtin_bit_cast(unsigned, f);
  u += 0x7fffu + ((u >> 16) & 1u);  // RNE
  unsigned short h = (unsigned short)(u >> 16);
  return __builtin_bit_cast(__bf16, h);
}

// pack two f32 -> two bf16 (truncation) in one v_perm
DEVINL unsigned pk2bf_trunc(float lo, float hi) {
  return __builtin_amdgcn_perm(__builtin_bit_cast(unsigned, hi),
                               __builtin_bit_cast(unsigned, lo), 0x07060302);
}

DEVINL void gl2lds16(const void* g, void* l) {
  __builtin_amdgcn_global_load_lds((gvoid_t*)g, (lvoid_t*)l, 16, 0, 0);
}

// Per-wave dtype self-detect: every wave loads the SAME 256 B of src
// (L2/L3 broadcast-hot) and votes on bf16-plausible exponents.
DEVINL int wave_detect(const unsigned* __restrict__ w) {
  const int l = threadIdx.x & 63;
  const unsigned word = w[l];
  const unsigned e = (word >> 7) & 0xFFu;
  const int vote = (e >= 0x70u && e <= 0x87u) ? 1 : 0;
  const unsigned long long m = __ballot(vote);
  return (__popcll(m) >= 32) ? 1 : 0;
}

// ---------------------------------------------------------------------------
// Fused prologue (one launch instead of memset+cvt_src+cvt_bias+cvt_wt):
//   blocks [0,4096):      src -> bf16
//   blocks [4096,4128):   biases -> f32 (+ block 4096 zeroes the attn counter)
//   blocks [4128,8224):   4 weights -> bf16 transposed (64x64 LDS tiles)
__global__ __launch_bounds__(256) void prologue(
    const void* __restrict__ src, __bf16* __restrict__ srcbf, int n8,
    const void* __restrict__ b0, const void* __restrict__ b1,
    const void* __restrict__ b2, const void* __restrict__ b3,
    float* __restrict__ biasf, const void* __restrict__ w0,
    const void* __restrict__ w1, const void* __restrict__ w2,
    const void* __restrict__ w3, __bf16* __restrict__ wt,
    int* __restrict__ cnt) {
  __shared__ __attribute__((aligned(16))) __bf16 tile[64][68];
  const int fl = wave_detect((const unsigned*)src);
  const int bi = blockIdx.x;
  if (bi < 4096) {  // src conversion
    const int i = bi * 256 + threadIdx.x;
    if (i >= n8) return;
    if (fl) {
      ((bf16x8*)srcbf)[i] = ((const bf16x8*)src)[i];
    } else {
      const float* f = (const float*)src + (size_t)i * 8;
      bf16x8v v;
#pragma unroll
      for (int j = 0; j < 8; ++j) v[j] = f2bf(f[j]);
      ((bf16x8*)srcbf)[i] = v;
    }
    return;
  }
  if (bi < 4128) {  // bias conversion + counter zero
    if (bi == 4096 && threadIdx.x == 0) *cnt = 0;
    const int i = (bi - 4096) * 256 + threadIdx.x;  // 0..8191
    const void* b = (i < 2048) ? b0 : (i < 4096) ? b1 : (i < 6144) ? b2 : b3;
    const int idx = i & 2047;
    biasf[i] = fl ? (float)((const __bf16*)b)[idx] : ((const float*)b)[idx];
    return;
  }
  // weight transpose: idx -> (z weight, by n-tile, bx k-tile)
  const int idx = bi - 4128;
  const int z = idx >> 10, rem = idx & 1023;
  const int by = rem >> 5, bx = rem & 31;
  const void* W = (z == 0) ? w0 : (z == 1) ? w1 : (z == 2) ? w2 : w3;
  __bf16* Wt = wt + (size_t)z * WSZ;
  const int tx = threadIdx.x & 63, ty = threadIdx.x >> 6;
  const int k0 = bx * 64, n0 = by * 64;
#pragma unroll
  for (int i = ty; i < 64; i += 4) {
    const size_t off = (size_t)(k0 + i) * CDIM + n0 + tx;
    const float v = fl ? (float)((const __bf16*)W)[off] : ((const float*)W)[off];
    tile[i][tx] = f2bf(v);
  }
  __syncthreads();
#pragma unroll
  for (int i = ty; i < 64; i += 4)
    Wt[(size_t)(n0 + i) * CDIM + k0 + tx] = tile[tx][i];
}

// ---------------------------------------------------------------------------
// Half-K PING-PONG GEMM, 48 KiB LDS. R10 fix vs R9: __launch_bounds__(512,4)
// instead of (512,6). R9's (512,6) hint forced the allocator to 40 VGPR ->
// total spill catastrophe (WRITE_SIZE 2.29 GB, 937 us, MfmaUtil 4.4%).
// R8 evidence: at (512,4) the compiler NATURALLY allocates 64 VGPR with
// zero spill. Per the m69 occupancy model (32 waves/CU at <=64 VGPR), 64
// VGPR permits 32 waves; with 48 KiB LDS the limiter is LDS: 3 blocks x
// 48 KiB = 144 <= 160 KiB -> 24 waves/CU WITHOUT any coercion. If the
// allocator instead picks 65-128, occupancy falls back to 2 blocks/CU =
// R8's proven 115-us regime — bounded downside.
// Schedule per K-tile (halves h0=2kt slot0, h0+1 slot1):
//   P1: ds_read slot0 (A+nf01) | stage h0+1 -> slot1 | lgkm-bar | MFMA | bar
//   P2: ds_read slot0 (nf23)   |                      lgkm-bar | MFMA |
//       vmcnt(0) certifies h0+1 | bar
//   P3: ds_read slot1 (A+nf01) | stage h0+2 -> slot0 | lgkm-bar | MFMA | bar
//   P4: ds_read slot1 (nf23)   |                      lgkm-bar | MFMA |
//       vmcnt(0) certifies h0+2 | bar
// Race-freedom: each phase's ds_reads are lgkm-drained before its MFMA, so
// the phase-close barrier certifies them chip-wide; slot-s staging is issued
// only after the barrier that postdates slot-s's last read.
// LDS pair-line layout + XOR involution identical to the R5-R9
// functionally-verified kernel; measured-zero bank conflicts.
template <int MODE>
__global__ __launch_bounds__(512, 4) void gemmring(
    const __bf16* __restrict__ A, const __bf16* __restrict__ Bt,
    const float* __restrict__ bias, __bf16* __restrict__ qb,
    __bf16* __restrict__ kb, __bf16* __restrict__ vtb,
    const unsigned* __restrict__ srcw, void* __restrict__ outp) {
  constexpr int K = CDIM;
  constexpr int NKT = K / 64;  // 32 K-tiles, 64 halves
  __shared__ __attribute__((aligned(16))) __bf16 Asl[2][128 * 32];
  __shared__ __attribute__((aligned(16))) __bf16 Bsl[2][256 * 32];

  const int tid = threadIdx.x;
  const int w = tid >> 6, l = tid & 63;
  const int quad = l >> 4, l16 = l & 15;
  const int wm = w >> 2, wn = w & 3;  // wave tile 64x64

  const int bid = blockIdx.x;
  const int bm = bid & 31, bn = bid >> 5;  // bm-fastest: B panel L2-shared
  const int m0 = bm * 128, n0 = bn * 256;

  // staging source pre-swizzle (inverse of the pair-line layout)
  const int ls = (tid & 7) ^ ((tid >> 3) & 7);
  const int rbase = 2 * (tid >> 3) + (ls >> 2);  // 0..127
  const int cb8 = (ls & 3) * 8;
  const __bf16* gAh = A + (size_t)(m0 + rbase) * K + cb8;
  const __bf16* gBh = Bt + (size_t)(n0 + rbase) * K + cb8;

  // fragment read addressing (per-lane constant)
  const int L2 = l16 >> 1;
  const int physr = (((l16 & 1) << 2) + quad) ^ L2;
  const int lane_e = L2 * 64 + physr * 8;  // element offset within slot

  __bf16* a0 = (__bf16*)Asl[0];
  __bf16* a1 = (__bf16*)Asl[1];
  __bf16* b0 = (__bf16*)Bsl[0];
  __bf16* b1 = (__bf16*)Bsl[1];

#define STAGE_A(dst, h)                                                   \
  gl2lds16(gAh + (size_t)(((h) >> 1) * 64 + ((h) & 1) * 32), (dst) + w * 512)
#define STAGE_B(dst, h, e)                                                \
  gl2lds16(gBh + (size_t)(e) * 128 * K +                                  \
               (((h) >> 1) * 64 + ((h) & 1) * 32),                        \
           (dst) + (e) * 4096 + w * 512)

  f32x4 acc[4][4];
#pragma unroll
  for (int i = 0; i < 4; ++i)
#pragma unroll
    for (int j = 0; j < 4; ++j) acc[i][j] = (f32x4){0.f, 0.f, 0.f, 0.f};

  // prologue: stage half 0 into slot0; drain; barrier.
  STAGE_A(a0, 0); STAGE_B(b0, 0, 0); STAGE_B(b0, 0, 1);
  asm volatile("s_waitcnt vmcnt(0)" ::: "memory");
  __builtin_amdgcn_sched_barrier(0);
  __builtin_amdgcn_s_barrier();

#define MFMA8(NF0)                                                        \
  __builtin_amdgcn_s_setprio(1);                                          \
  _Pragma("unroll") for (int mi = 0; mi < 4; ++mi) {                      \
    acc[mi][(NF0)] = __builtin_amdgcn_mfma_f32_16x16x32_bf16(             \
        afr[mi], bfr[0], acc[mi][(NF0)], 0, 0, 0);                        \
    acc[mi][(NF0) + 1] = __builtin_amdgcn_mfma_f32_16x16x32_bf16(         \
        afr[mi], bfr[1], acc[mi][(NF0) + 1], 0, 0, 0);                    \
  }                                                                       \
  __builtin_amdgcn_s_setprio(0);

#define LGKM_BAR()                                                        \
  __builtin_amdgcn_s_barrier();                                           \
  asm volatile("s_waitcnt lgkmcnt(0)" ::: "memory");                      \
  __builtin_amdgcn_sched_barrier(0)

#define VM0_BAR()                                                         \
  asm volatile("s_waitcnt vmcnt(0)" ::: "memory");                        \
  __builtin_amdgcn_sched_barrier(0);                                      \
  __builtin_amdgcn_s_barrier()

  for (int kt = 0; kt < NKT; ++kt) {
    const int h0 = 2 * kt;
    const bool st = (kt < NKT - 1);
    bf16x8 afr[4], bfr[2];

    // ---- P1: slot0 (h0), nf0-1; stage h0+1 -> slot1 (slot1's last read
    //      was prev-P4, closed by the prev-P4 barrier).
#pragma unroll
    for (int mi = 0; mi < 4; ++mi)
      afr[mi] = *(const bf16x8*)&a0[(wm * 64 + mi * 16) * 32 + lane_e];
    bfr[0] = *(const bf16x8*)&b0[(wn * 64 + 0 * 16) * 32 + lane_e];
    bfr[1] = *(const bf16x8*)&b0[(wn * 64 + 1 * 16) * 32 + lane_e];
    STAGE_A(a1, h0 + 1); STAGE_B(b1, h0 + 1, 0); STAGE_B(b1, h0 + 1, 1);
    LGKM_BAR();
    MFMA8(0)
    __builtin_amdgcn_s_barrier();

    // ---- P2: slot0 (h0), nf2-3; end-wait certifies h0+1 for P3.
    bfr[0] = *(const bf16x8*)&b0[(wn * 64 + 2 * 16) * 32 + lane_e];
    bfr[1] = *(const bf16x8*)&b0[(wn * 64 + 3 * 16) * 32 + lane_e];
    LGKM_BAR();
    MFMA8(2)
    VM0_BAR();

    // ---- P3: slot1 (h0+1), nf0-1; stage h0+2 -> slot0 (slot0's last read
    //      was P2, closed by the P2-end barrier).
#pragma unroll
    for (int mi = 0; mi < 4; ++mi)
      afr[mi] = *(const bf16x8*)&a1[(wm * 64 + mi * 16) * 32 + lane_e];
    bfr[0] = *(const bf16x8*)&b1[(wn * 64 + 0 * 16) * 32 + lane_e];
    bfr[1] = *(const bf16x8*)&b1[(wn * 64 + 1 * 16) * 32 + lane_e];
    if (st) { STAGE_A(a0, h0 + 2); STAGE_B(b0, h0 + 2, 0); STAGE_B(b0, h0 + 2, 1); }
    LGKM_BAR();
    MFMA8(0)
    __builtin_amdgcn_s_barrier();

    // ---- P4: slot1 (h0+1), nf2-3; end-wait certifies h0+2 for next P1.
    bfr[0] = *(const bf16x8*)&b1[(wn * 64 + 2 * 16) * 32 + lane_e];
    bfr[1] = *(const bf16x8*)&b1[(wn * 64 + 3 * 16) * 32 + lane_e];
    LGKM_BAR();
    MFMA8(2)
    VM0_BAR();
  }
#undef MFMA8
#undef LGKM_BAR
#undef VM0_BAR
#undef STAGE_A
#undef STAGE_B

  if (MODE == 0) {
    // QKV scatter: Q,K -> [b,h,t,d]; V -> [b,h,d,t] (bf16x4). BN=256
    // divides 2048 -> mat uniform per block.
    const int mat = n0 >> 11;  // 0=Q 1=K 2=V
#pragma unroll
    for (int nf = 0; nf < 4; ++nf) {
      const int n = n0 + wn * 64 + nf * 16 + l16;  // 0..6143
      const int nn = n & 2047;
      const int h = nn >> 7, d = nn & 127;
      const float bv = bias[n];
#pragma unroll
      for (int mi = 0; mi < 4; ++mi) {
        const int mbase = m0 + wm * 64 + mi * 16 + quad * 4;
        const int bb = mbase >> 11, t = mbase & 2047;
        if (mat == 2) {
          bf16x4v v4;
#pragma unroll
          for (int r = 0; r < 4; ++r) v4[r] = f2bf(acc[mi][nf][r] + bv);
          *(bf16x4*)&vtb[((size_t)(bb * NHEAD + h) * DHEAD + d) * TDIM + t] = v4;
        } else {
          __bf16* op = (mat == 0) ? qb : kb;
#pragma unroll
          for (int r = 0; r < 4; ++r)
            op[((size_t)(bb * NHEAD + h) * TDIM + t + r) * DHEAD + d] =
                f2bf(acc[mi][nf][r] + bv);
        }
      }
    }
  } else {
    const int ofl = wave_detect(srcw);
#pragma unroll
    for (int nf = 0; nf < 4; ++nf) {
      const int n = n0 + wn * 64 + nf * 16 + l16;
      const float bv = bias[n];
#pragma unroll
      for (int mi = 0; mi < 4; ++mi) {
#pragma unroll
        for (int r = 0; r < 4; ++r) {
          const int m = m0 + wm * 64 + mi * 16 + quad * 4 + r;
          const float v = acc[mi][nf][r] + bv;
          if (ofl) ((__bf16*)outp)[(size_t)m * CDIM + n] = f2bf(v);
          else     ((float*)outp)[(size_t)m * CDIM + n] = v;
        }
      }
    }
  }
}

// ---------------------------------------------------------------------------
// Flash-style causal attention (R7 form: setprio around MFMA clusters,
// defer-max THR=8). Persistent blocks + work-stealing, LDS-staged K/V,
// 2 lgkm-only barriers per s-block, register-double-buffered staging.
// (256,2): kernel needs ~180 regs/wave — forcing 3 waves/EU spills.
__global__ __launch_bounds__(256, 2) void attn(
    const __bf16* __restrict__ Q, const __bf16* __restrict__ K,
    const __bf16* __restrict__ Vt, __bf16* __restrict__ ctx,
    int* __restrict__ cnt) {
  constexpr float CSC = 0.12753139726f;  // log2(e)/sqrt(128)
  __shared__ __attribute__((aligned(16))) __bf16 Kls[64 * 128];   // [s][d]
  __shared__ __attribute__((aligned(16))) __bf16 Vls[128 * 64];   // [d][s]
  __shared__ __attribute__((aligned(16))) __bf16 Pls[4][32 * 64]; // [t][s]
  __shared__ int jobLds;

  const int tid = threadIdx.x;
  const int w = tid >> 6, l = tid & 63, quad = l >> 4, l16 = l & 15;

  const int krow = tid >> 4;                 // 0..15, +16 per pass
  const int kcol = tid & 15;
  const int kldsoff = ((kcol ^ krow) * 8);
  const int vrow = tid >> 3;                 // 0..31, +32 per pass
  const int vcol = tid & 7;
  const int vldsoff = ((vcol ^ (vrow & 7)) * 8);

  for (;;) {
    __syncthreads();
    if (tid == 0) jobLds = atomicAdd(cnt, 1);
    __syncthreads();
    const int j = jobLds;
    if (j >= 512) break;
    const int qt = 15 - (j >> 5);   // all qt=15 jobs first (LPT)
    const int bh = j & 31;
    const int t0w = qt * 128 + w * 32;
    const __bf16* Qbh = Q + (size_t)bh * TDIM * DHEAD;
    const __bf16* Kbh = K + (size_t)bh * TDIM * DHEAD;
    const __bf16* Vbh = Vt + (size_t)bh * TDIM * DHEAD;

    bf16x8 qf[2][4];
#pragma unroll
    for (int tt = 0; tt < 2; ++tt)
#pragma unroll
      for (int ks = 0; ks < 4; ++ks)
        qf[tt][ks] = *(const bf16x8*)(Qbh +
                     (size_t)(t0w + tt * 16 + l16) * DHEAD + ks * 32 + quad * 8);

    f32x4 oacc[8][2];
#pragma unroll
    for (int dt = 0; dt < 8; ++dt)
#pragma unroll
      for (int tt = 0; tt < 2; ++tt) oacc[dt][tt] = (f32x4){0.f, 0.f, 0.f, 0.f};
    float mrow[2] = {-1e30f, -1e30f};
    float lrow[2] = {0.f, 0.f};

    const int nsb = 2 * (qt + 1);

    // prefetch s-block 0 into regs
    bf16x8 kr[4], vr[4];
#pragma unroll
    for (int p = 0; p < 4; ++p)
      kr[p] = *(const bf16x8*)(Kbh + (size_t)(p * 16 + krow) * DHEAD + kcol * 8);
#pragma unroll
    for (int p = 0; p < 4; ++p)
      vr[p] = *(const bf16x8*)(Vbh + (size_t)(p * 32 + vrow) * TDIM + vcol * 8);

    for (int sb = 0; sb < nsb; ++sb) {
      const int s0 = sb * 64;
      BARRIER_LGKM();  // prior iteration's LDS reads complete
#pragma unroll
      for (int p = 0; p < 4; ++p)
        *(bf16x8*)&Kls[(p * 16 + krow) * 128 + kldsoff] = kr[p];
#pragma unroll
      for (int p = 0; p < 4; ++p)
        *(bf16x8*)&Vls[(p * 32 + vrow) * 64 + vldsoff] = vr[p];
      if (sb + 1 < nsb) {
        const int s1 = s0 + 64;
#pragma unroll
        for (int p = 0; p < 4; ++p)
          kr[p] = *(const bf16x8*)(Kbh + (size_t)(s1 + p * 16 + krow) * DHEAD +
                                   kcol * 8);
#pragma unroll
        for (int p = 0; p < 4; ++p)
          vr[p] = *(const bf16x8*)(Vbh + (size_t)(p * 32 + vrow) * TDIM + s1 +
                                   vcol * 8);
      }
      BARRIER_LGKM();  // staging visible; prefetch loads remain in flight
      if (s0 > t0w + 31) continue;  // fully masked for this wave

      // S^T = K.Q^T : D[row=s: quad*4+r][col=t: l16]
      f32x4 sacc[4][2];
#pragma unroll
      for (int st = 0; st < 4; ++st)
#pragma unroll
        for (int tt = 0; tt < 2; ++tt) sacc[st][tt] = (f32x4){0.f, 0.f, 0.f, 0.f};
      __builtin_amdgcn_s_setprio(1);
#pragma unroll
      for (int ks = 0; ks < 4; ++ks) {
        bf16x8 kf[4];
#pragma unroll
        for (int st = 0; st < 4; ++st)
          kf[st] = *(const bf16x8*)&Kls[(st * 16 + l16) * 128 +
                                        (((ks * 4 + quad) ^ l16) * 8)];
#pragma unroll
        for (int st = 0; st < 4; ++st)
#pragma unroll
          for (int tt = 0; tt < 2; ++tt)
            sacc[st][tt] = __builtin_amdgcn_mfma_f32_16x16x32_bf16(
                kf[st], qf[tt][ks], sacc[st][tt], 0, 0, 0);
      }
      __builtin_amdgcn_s_setprio(0);
      if (s0 + 63 > t0w) {  // causal mask near diagonal
#pragma unroll
        for (int st = 0; st < 4; ++st)
#pragma unroll
          for (int tt = 0; tt < 2; ++tt)
#pragma unroll
            for (int r = 0; r < 4; ++r) {
              const int s = s0 + st * 16 + quad * 4 + r;
              const int t = t0w + tt * 16 + l16;
              if (s > t) sacc[st][tt][r] = -1e30f;
            }
      }
      // online softmax per t-column (defer-max: rescale only when growth
      // exceeds 8 exp2-units; P stays bounded by 2^8)
#pragma unroll
      for (int tt = 0; tt < 2; ++tt) {
        float vm = -1e30f;
#pragma unroll
        for (int st = 0; st < 4; ++st)
#pragma unroll
          for (int r = 0; r < 4; ++r) vm = fmaxf(vm, sacc[st][tt][r]);
        vm = fmaxf(vm, __shfl_xor(vm, 16));
        vm = fmaxf(vm, __shfl_xor(vm, 32));
        if (__ballot((vm - mrow[tt]) * CSC > 8.0f)) {
          const float mn = fmaxf(mrow[tt], vm);
          const float alpha = exp2f((mrow[tt] - mn) * CSC);
          lrow[tt] *= alpha;
#pragma unroll
          for (int dt = 0; dt < 8; ++dt)
#pragma unroll
            for (int r = 0; r < 4; ++r) oacc[dt][tt][r] *= alpha;
          mrow[tt] = mn;
        }
        const float mcur = mrow[tt];
        float rs = 0.f;
#pragma unroll
        for (int st = 0; st < 4; ++st) {
          const float p0 = exp2f((sacc[st][tt][0] - mcur) * CSC);
          const float p1 = exp2f((sacc[st][tt][1] - mcur) * CSC);
          const float p2 = exp2f((sacc[st][tt][2] - mcur) * CSC);
          const float p3 = exp2f((sacc[st][tt][3] - mcur) * CSC);
          rs += (p0 + p1) + (p2 + p3);
          u32x2 pk = {pk2bf_trunc(p0, p1), pk2bf_trunc(p2, p3)};
          *(u32x2*)&Pls[w][(tt * 16 + l16) * 64 +
                           (((st * 2 + (quad >> 1)) ^ (l16 & 7)) * 8) +
                           (quad & 1) * 4] = pk;
        }
        rs += __shfl_xor(rs, 16);
        rs += __shfl_xor(rs, 32);
        lrow[tt] += rs;
      }
      // intra-wave P write->read ordering (wave-private region, no barrier)
      asm volatile("s_waitcnt lgkmcnt(0)" ::: "memory");
      // O^T += V^T.P^T : D[row=d][col=t]
      __builtin_amdgcn_s_setprio(1);
#pragma unroll
      for (int ks = 0; ks < 2; ++ks) {
        bf16x8 pf[2];
#pragma unroll
        for (int tt = 0; tt < 2; ++tt)
          pf[tt] = *(const bf16x8*)&Pls[w][(tt * 16 + l16) * 64 +
                                           (((ks * 4 + quad) ^ (l16 & 7)) * 8)];
#pragma unroll
        for (int dt = 0; dt < 8; ++dt) {
          const bf16x8 vf =
              *(const bf16x8*)&Vls[(dt * 16 + l16) * 64 +
                                   (((ks * 4 + quad) ^ (l16 & 7)) * 8)];
#pragma unroll
          for (int tt = 0; tt < 2; ++tt)
            oacc[dt][tt] = __builtin_amdgcn_mfma_f32_16x16x32_bf16(
                vf, pf[tt], oacc[dt][tt], 0, 0, 0);
        }
      }
      __builtin_amdgcn_s_setprio(0);
    }

    // epilogue: O^T[d][t]/l -> ctx[b][t][h*128+d], bf16x4 stores
    const int b = bh >> 4, h = bh & 15;
#pragma unroll
    for (int tt = 0; tt < 2; ++tt) {
      const float rinv = 1.0f / lrow[tt];
      const int t = t0w + tt * 16 + l16;
      __bf16* cp = ctx + ((size_t)(b * TDIM + t)) * CDIM + h * DHEAD;
#pragma unroll
      for (int dt = 0; dt < 8; ++dt) {
        bf16x4v v4;
#pragma unroll
        for (int r = 0; r < 4; ++r) v4[r] = f2bf(oacc[dt][tt][r] * rinv);
        *(bf16x4*)&cp[dt * 16 + quad * 4] = v4;
      }
    }
  }
}

// ---------------------------------------------------------------------------
extern "C" void kernel_launch(void* const* d_in, const int* in_sizes, int n_in,
                              void* d_out, int out_size, void* d_ws,
                              size_t ws_size, hipStream_t stream) {
  const void* src = d_in[0];
  const void* Wq = d_in[1];
  const void* bq = d_in[2];
  const void* Wk = d_in[3];
  const void* bk = d_in[4];
  const void* Wv = d_in[5];
  const void* bv = d_in[6];
  const void* Wo = d_in[7];
  const void* bo = d_in[8];

  char* wsb = (char*)d_ws;
  int* cnt = (int*)(wsb + 128);           // +128 (work-steal counter)
  __bf16* srcbf = (__bf16*)(wsb + 256);
  __bf16* wqt = srcbf + XSZ;              // q,k,v,o transposed, contiguous
  __bf16* wot = wqt + 3 * WSZ;
  __bf16* qb = wot + WSZ;                 // [B*NH][T][D]
  __bf16* kb = qb + XSZ;                  // [B*NH][T][D]
  __bf16* vtb = kb + XSZ;                 // [B*NH][D][T]
  float* biasf = (float*)(vtb + XSZ);     // 4 x 2048 f32
  __bf16* ctx = srcbf;                    // reuse (src consumed by then)

  // fused prologue: src cvt (4096) + bias cvt/cnt-zero (32) + wt transpose
  // (4096) = 8224 blocks, one launch.
  prologue<<<8224, 256, 0, stream>>>(src, srcbf, (int)(XSZ / 8), bq, bk, bv,
                                     bo, biasf, Wq, Wk, Wv, Wo, wqt, cnt);
  // fused QKV: M=4096, N=6144, BM=128 x BN=256 -> 32x24 = 768 blocks
  // (if the allocator lands at <=64 VGPR: 3 blocks/CU -> one full round)
  gemmring<0><<<768, 512, 0, stream>>>(srcbf, wqt, biasf, qb, kb, vtb,
                                       nullptr, nullptr);
  attn<<<512, 256, 0, stream>>>(qb, kb, vtb, ctx, cnt);
  // out-proj: M=4096, N=2048 -> 32x8 = 256 blocks
  gemmring<1><<<256, 512, 0, stream>>>(ctx, wot, biasf + 6144, nullptr,
                                       nullptr, nullptr, (const unsigned*)src,
                                       d_out);
}